// Round 5
// baseline (621.762 us; speedup 1.0000x reference)
//
#include <hip/hip_runtime.h>
#include <math.h>

typedef _Float16 h16;
typedef _Float16 half8 __attribute__((ext_vector_type(8)));
typedef float f32x4 __attribute__((ext_vector_type(4)));

#define BATCH 16
#define CH 256
#define EPSBN 1e-5f

constexpr size_t WE_STRIDE = (size_t)CH * CH * 9;   // 589,824 elems per expert
constexpr int REG = 2120;   // halves per ci-octet region: 265 sp slots * 8

__device__ __forceinline__ float silu_(float v) {
    return v * (1.0f / (1.0f + __expf(-v)));
}

// Implicit-GEMM 3x3 conv (pad 1) over NHWC f16 input, 9 tap-shifted GEMMs.
// Tile: 128 sp (2 rows) x 128 co. 4 waves, each owns a distinct 32-co slice.
// All 18 weight fragments for a ci-chunk are hoisted (loaded once, up front)
// so the tap loop is pure LDS-read + MFMA.
// MFMA contract (m89/m91): A[m=l15][k=quad*8+j], B[k=quad*8+j][n=l15], D[m=quad*4+r][n=l15]
template<int MODE>
__global__ __launch_bounds__(256, 3)
void conv_mfma(const h16* __restrict__ xin,
               const h16* __restrict__ wt,
               const float* __restrict__ bng, const float* __restrict__ bnb,
               const float* __restrict__ bnm, const float* __restrict__ bnv,
               const float* __restrict__ resid,
               void* __restrict__ outv)
{
    __shared__ h16 xt[4 * REG];   // 16,960 B

    const int t    = threadIdx.x;
    const int bx   = blockIdx.x;    // 32 spatial tiles (2 rows each)
    const int by   = blockIdx.y;    // 2 co tiles
    const int bz   = blockIdx.z;    // batch
    const int h0   = bx * 2;
    const int co0  = by * 128;
    const int wv   = t >> 6;        // wave owns co slice wv*32
    const int lane = t & 63;
    const int quad = lane >> 4;
    const int l15  = lane & 15;

    f32x4 acc[16];
    #pragma unroll
    for (int i = 0; i < 16; ++i) {
        f32x4 z = {0.f, 0.f, 0.f, 0.f};
        acc[i] = z;
    }

    // lane weight base: co = co0 + wv*32 + f*16 + l15, ci = ci0 + quad*8
    const h16* wrow = wt + ((MODE == 1) ? (size_t)bz * 9 * 65536 : (size_t)0)
                         + ((size_t)(co0 + wv * 32 + l15) << 8)
                         + (size_t)(quad * 8);
    // per-lane LDS base; all frag reads are compile-time offsets from this
    const h16* xlane = xt + quad * REG + l15 * 8;

    for (int ci0 = 0; ci0 < CH; ci0 += 32) {
        __syncthreads();
        // stage 4 halo rows x 66 halo cols x 32 ci: 1056 half8 tasks, cig-minor
        #pragma unroll
        for (int k = 0; k < 5; ++k) {
            int idx = t + k * 256;
            if (idx < 1056) {
                int cig = idx & 3;
                int sp  = idx >> 2;            // row*66+col, 0..263
                int row = sp / 66;
                int col = sp - row * 66;
                int gh = h0 - 1 + row, gw = col - 1;
                half8 v = {0, 0, 0, 0, 0, 0, 0, 0};
                if ((unsigned)gh < 64u && (unsigned)gw < 64u)
                    v = *(const half8*)(xin + (((size_t)(bz * 64 + gh) << 6) + gw) * 256
                                            + ci0 + cig * 8);
                *(half8*)(xt + cig * REG + sp * 8) = v;
            }
        }

        // ---- hoist ALL weight fragments for this chunk (18 independent loads,
        // issued back-to-back; single wait) ----
        const h16* wc = wrow + ci0;
        half8 wfa[9][2];
        #pragma unroll
        for (int tap = 0; tap < 9; ++tap)
            #pragma unroll
            for (int f = 0; f < 2; ++f)
                wfa[tap][f] = *(const half8*)(wc + (size_t)tap * 65536 + f * 4096);

        __syncthreads();

        #pragma unroll
        for (int kh = 0; kh < 3; ++kh)
        #pragma unroll
        for (int kw = 0; kw < 3; ++kw) {
            const int tap = kh * 3 + kw;
            half8 xf[8];
            #pragma unroll
            for (int i = 0; i < 8; ++i)
                xf[i] = *(const half8*)(xlane + ((kh + (i >> 2)) * 66 + (i & 3) * 16 + kw) * 8);
            if (MODE == 0) {
                #pragma unroll
                for (int i = 0; i < 8; ++i)
                    #pragma unroll
                    for (int j = 0; j < 2; ++j)
                        acc[i * 2 + j] = __builtin_amdgcn_mfma_f32_16x16x32_f16(
                            xf[i], wfa[tap][j], acc[i * 2 + j], 0, 0, 0);
            } else {
                #pragma unroll
                for (int i = 0; i < 2; ++i)
                    #pragma unroll
                    for (int j = 0; j < 8; ++j)
                        acc[i * 8 + j] = __builtin_amdgcn_mfma_f32_16x16x32_f16(
                            wfa[tap][i], xf[j], acc[i * 8 + j], 0, 0, 0);
            }
        }
    }

    if (MODE == 0) {
        // D[sp][co] -> y f16 NHWC, BN+SiLU
        h16* yout = (h16*)outv;
        float sc[2], sh[2];
        #pragma unroll
        for (int j = 0; j < 2; ++j) {
            int c = co0 + wv * 32 + j * 16 + l15;
            float s = bng[c] * rsqrtf(bnv[c] + EPSBN);
            sc[j] = s; sh[j] = bnb[c] - bnm[c] * s;
        }
        #pragma unroll
        for (int i = 0; i < 8; ++i)
            #pragma unroll
            for (int r = 0; r < 4; ++r) {
                int spL = i * 16 + quad * 4 + r;
                int h = h0 + (spL >> 6), w = spL & 63;
                size_t base = (((size_t)(bz * 64 + h) << 6) + w) * 256
                            + co0 + wv * 32 + l15;
                #pragma unroll
                for (int j = 0; j < 2; ++j) {
                    float v = acc[i * 2 + j][r] * sc[j] + sh[j];
                    yout[base + j * 16] = (h16)silu_(v);
                }
            }
    } else {
        // D[co][sp] -> out fp32 NCHW, resid + BN+SiLU
        float* outp = (float*)outv;
        #pragma unroll
        for (int i = 0; i < 2; ++i) {
            float sc[4], sh[4];
            #pragma unroll
            for (int r = 0; r < 4; ++r) {
                int c = co0 + wv * 32 + i * 16 + quad * 4 + r;
                float s = bng[c] * rsqrtf(bnv[c] + EPSBN);
                sc[r] = s; sh[r] = bnb[c] - bnm[c] * s;
            }
            #pragma unroll
            for (int j = 0; j < 8; ++j) {
                int spL = j * 16 + l15;
                int h = h0 + (spL >> 6), w = spL & 63;
                #pragma unroll
                for (int r = 0; r < 4; ++r) {
                    int c = co0 + wv * 32 + i * 16 + quad * 4 + r;
                    size_t idx = ((size_t)(bz * CH + c) << 12) + (h << 6) + w;
                    float v = acc[i * 8 + j][r] * sc[r] + sh[r];
                    outp[idx] = resid[idx] + silu_(v);
                }
            }
        }
    }
}

// x fp32 NCHW -> xh f16 NHWC (LDS-tiled transpose). Block = (cg 64-ch group, h, b).
__global__ __launch_bounds__(256)
void prep_x(const float* __restrict__ x, h16* __restrict__ xh) {
    __shared__ float lt[64][65];
    int cg = blockIdx.x, h = blockIdx.y, b = blockIdx.z;
    int t = threadIdx.x;
    {
        int cl = t >> 2, wq = t & 3;
        const float4* src = (const float4*)(x + (((size_t)(b * CH + cg * 64 + cl)) << 12)
                                              + ((size_t)h << 6));
        #pragma unroll
        for (int k = 0; k < 4; ++k) {
            int w4 = wq + k * 4;
            float4 v = src[w4];
            lt[cl][w4 * 4 + 0] = v.x;
            lt[cl][w4 * 4 + 1] = v.y;
            lt[cl][w4 * 4 + 2] = v.z;
            lt[cl][w4 * 4 + 3] = v.w;
        }
    }
    __syncthreads();
    {
        int wl = t >> 2, cq = t & 3;
        half8 a2[2];
        h16* ap = (h16*)a2;
        #pragma unroll
        for (int m = 0; m < 16; ++m) ap[m] = (h16)lt[cq * 16 + m][wl];
        size_t base = ((((size_t)(b * 64 + h)) << 6) + wl) * 256 + cg * 64 + cq * 16;
        *(half8*)(xh + base)     = a2[0];
        *(half8*)(xh + base + 8) = a2[1];
    }
}

// w1 [co][ci][9] fp32 -> w1t [tap][co][ci] f16
__global__ void prep_w1(const float* __restrict__ w1, h16* __restrict__ w1t) {
    int pair = blockIdx.x * 256 + threadIdx.x;   // co*256+ci
    #pragma unroll
    for (int tap = 0; tap < 9; ++tap)
        w1t[((size_t)tap << 16) + pair] = (h16)w1[(size_t)pair * 9 + tap];
}

// part[slice][b][c] = partial sum over 256 sp of y NHWC (vectorized, no atomics)
__global__ __launch_bounds__(256)
void pool_kernel(const h16* __restrict__ y, float* __restrict__ part) {
    __shared__ float red[8][256];
    int slice = blockIdx.x, b = blockIdx.y;
    int t = threadIdx.x;
    int oct = t & 31, ss = t >> 5;
    float a[8];
    #pragma unroll
    for (int k = 0; k < 8; ++k) a[k] = 0.f;
    const h16* p = y + ((size_t)(b * 4096 + slice * 256 + ss)) * 256 + oct * 8;
    #pragma unroll 4
    for (int i = 0; i < 32; ++i) {
        half8 v = *(const half8*)(p + (size_t)i * 8 * 256);
        #pragma unroll
        for (int k = 0; k < 8; ++k) a[k] += (float)v[k];
    }
    #pragma unroll
    for (int k = 0; k < 8; ++k) red[ss][oct * 8 + k] = a[k];
    __syncthreads();
    float s = 0.f;
    #pragma unroll
    for (int q = 0; q < 8; ++q) s += red[q][t];
    part[((size_t)slice * BATCH + b) * 256 + t] = s;
}

__global__ void routing_kernel(const float* __restrict__ part,
                               const float* __restrict__ wr,
                               const float* __restrict__ br,
                               float* __restrict__ routing) {
    int t = threadIdx.x;
    if (t < 64) {
        int b = t >> 2, e = t & 3;
        float s = 0.f;
        for (int c = 0; c < 256; ++c) {
            float p = 0.f;
            for (int sl = 0; sl < 16; ++sl)
                p += part[((size_t)sl * BATCH + b) * 256 + c];
            s += p * wr[e * 256 + c];
        }
        s = s * (1.f / 4096.f) + br[e];
        routing[t] = 1.f / (1.f + __expf(-s));
    }
}

// wt2[b][tap][co][ci] f16 = sum_e routing[b][e] * w_e[e][(co*256+ci)*9+tap]
__global__ __launch_bounds__(256)
void kern_gen(const float* __restrict__ w_e,
              const float* __restrict__ routing,
              h16* __restrict__ wt2) {
    __shared__ float lw[4 * 2304];   // 36,864 B
    __shared__ float rsh[64];
    int t = threadIdx.x;
    int pair0 = blockIdx.x * 256;
    if (t < 64) rsh[t] = routing[t];
    #pragma unroll
    for (int e = 0; e < 4; ++e) {
        const float4* src = (const float4*)(w_e + (size_t)e * WE_STRIDE + (size_t)pair0 * 9);
        #pragma unroll
        for (int k = 0; k < 3; ++k) {
            int idx = t + k * 256;
            if (idx < 576) {
                float4 v = src[idx];
                float* d = &lw[e * 2304 + idx * 4];
                d[0] = v.x; d[1] = v.y; d[2] = v.z; d[3] = v.w;
            }
        }
    }
    __syncthreads();
    float wv[4][9];
    #pragma unroll
    for (int e = 0; e < 4; ++e)
        #pragma unroll
        for (int k = 0; k < 9; ++k)
            wv[e][k] = lw[e * 2304 + t * 9 + k];
    for (int b = 0; b < 16; ++b) {
        float r0 = rsh[b * 4 + 0], r1 = rsh[b * 4 + 1];
        float r2 = rsh[b * 4 + 2], r3 = rsh[b * 4 + 3];
        #pragma unroll
        for (int tap = 0; tap < 9; ++tap) {
            float s = r0 * wv[0][tap] + r1 * wv[1][tap]
                    + r2 * wv[2][tap] + r3 * wv[3][tap];
            wt2[((size_t)(b * 9 + tap) << 16) + pair0 + t] = (h16)s;
        }
    }
}

extern "C" void kernel_launch(void* const* d_in, const int* in_sizes, int n_in,
                              void* d_out, int out_size, void* d_ws, size_t ws_size,
                              hipStream_t stream) {
    const float* x    = (const float*)d_in[0];
    const float* w1   = (const float*)d_in[1];
    const float* bn1g = (const float*)d_in[2];
    const float* bn1b = (const float*)d_in[3];
    const float* bn1m = (const float*)d_in[4];
    const float* bn1v = (const float*)d_in[5];
    const float* wr   = (const float*)d_in[6];
    const float* br   = (const float*)d_in[7];
    const float* w_e  = (const float*)d_in[8];
    const float* bn2g = (const float*)d_in[9];
    const float* bn2b = (const float*)d_in[10];
    const float* bn2m = (const float*)d_in[11];
    const float* bn2v = (const float*)d_in[12];

    char* w = (char*)d_ws;
    h16*   xh      = (h16*)(w);                   // 33,554,432 B (x as f16 NHWC)
    h16*   y       = (h16*)(w + 33554432);        // 33,554,432 B (f16 NHWC)
    h16*   w1t     = (h16*)(w + 67108864);        //  1,179,648 B
    h16*   wt2     = (h16*)(w + 68288512);        // 18,874,368 B
    float* part    = (float*)(w + 87162880);      //    262,144 B
    float* routing = (float*)(w + 87425024);      //        256 B

    prep_x<<<dim3(4, 64, BATCH), 256, 0, stream>>>(x, xh);
    prep_w1<<<dim3(256), 256, 0, stream>>>(w1, w1t);

    dim3 cgrid(32, 2, BATCH);   // sp-tiles x co-tiles x batch
    conv_mfma<0><<<cgrid, 256, 0, stream>>>(xh, w1t, bn1g, bn1b, bn1m, bn1v,
                                            nullptr, y);
    pool_kernel<<<dim3(16, BATCH), 256, 0, stream>>>(y, part);
    routing_kernel<<<dim3(1), 64, 0, stream>>>(part, wr, br, routing);
    kern_gen<<<dim3(256), 256, 0, stream>>>(w_e, routing, wt2);
    conv_mfma<1><<<cgrid, 256, 0, stream>>>(y, wt2, bn2g, bn2b, bn2m, bn2v,
                                            x, (float*)d_out);
}